// Round 3
// baseline (7404.353 us; speedup 1.0000x reference)
//
#include <hip/hip_runtime.h>

// ---------------------------------------------------------------------------
// SentenceDecoder on MI355X — float32 I/O (reference dtype), scalar f32 math.
// Dims: B=64, T=32, P=64, E=H=512, V=30000, IN=1568, rows = T*B = 2048.
// Output layout (flat f32): logp [64][32][30000] | attn [64][32][65] | slp [64]
// ---------------------------------------------------------------------------

#define DEV __device__ __forceinline__

// ---------------------------------------------------------------------------
// image mean over P=64
// ---------------------------------------------------------------------------
__global__ __launch_bounds__(256)
void mean_kernel(const float* __restrict__ image, float* __restrict__ imean)
{
  int b = blockIdx.x;
  for (int e = threadIdx.x; e < 512; e += 256) {
    float s = 0.f;
    for (int p = 0; p < 64; ++p) s += image[(size_t)(b * 64 + p) * 512 + e];
    imean[b * 512 + e] = s * (1.0f / 64.0f);
  }
}

// ---------------------------------------------------------------------------
// X[t*64+b] = [imean(512) | vp(16) | label(16) | topic(512) | emb[tok](512)]
// ---------------------------------------------------------------------------
__global__ __launch_bounds__(256)
void prep_kernel(const float* __restrict__ imean, const float* __restrict__ vp,
                 const float* __restrict__ lab, const float* __restrict__ topic,
                 const int* __restrict__ text, const float* __restrict__ wemb,
                 float* __restrict__ X)
{
  int b = blockIdx.x;
  for (int t = 0; t < 32; ++t) {
    float* xr = X + ((size_t)t * 64 + b) * 1568;
    int tok = (t == 0) ? 0 : text[b * 32 + t - 1];
    for (int e = threadIdx.x; e < 512; e += 256) {
      xr[e] = imean[b * 512 + e];
      xr[544 + e] = topic[b * 512 + e];
      xr[1056 + e] = wemb[(size_t)tok * 512 + e];
    }
    if (threadIdx.x < 16) {
      xr[512 + threadIdx.x] = vp[b * 16 + threadIdx.x];
      xr[528 + threadIdx.x] = lab[b * 16 + threadIdx.x];
    }
  }
}

// ---------------------------------------------------------------------------
// NT GEMM: C[m,n] = act( A[m,:].W[n,:] + bias1[n] (+bias2[n]) )
// A: M x K f32 (lda), W: N x K f32 (ldw).  256 threads = 256 cols, ROWS rows
// per block; A tile staged in dynamic LDS [K][ROWS+4] (padded, 16B-aligned
// rows so float4 broadcast reads work).  act: 0 none, 1 relu, 2 tanh.
// vmode=1: vocab — divide by temp[b], store to out[b][t][n] (row = t*64+b).
// ---------------------------------------------------------------------------
template<int ROWS>
__global__ void gemm_tmpl(const float* __restrict__ A, int lda,
                          const float* __restrict__ W, int ldw,
                          const float* __restrict__ bias1,
                          const float* __restrict__ bias2,
                          float* __restrict__ C, int ldc,
                          int M, int N, int K, int act, int vmode,
                          const float* __restrict__ temp)
{
  constexpr int RP = ROWS + 4;            // padded LDS row stride (16B-aligned)
  extern __shared__ __align__(16) float Ash[];   // [K][RP]
  const int tid = threadIdx.x;
  const int m0 = blockIdx.y * ROWS;
  const int n0 = blockIdx.x * 256;

  for (int idx = tid; idx < ROWS * K; idx += 256) {
    int r = idx / K, k = idx - r * K;     // consecutive lanes -> consecutive k
    int rr = m0 + r; if (rr >= M) rr = M - 1;
    Ash[k * RP + r] = A[(size_t)rr * lda + k];
  }
  __syncthreads();

  int n = n0 + tid;
  if (n >= N) return;

  float4 acc[ROWS / 4];
#pragma unroll
  for (int q = 0; q < ROWS / 4; ++q) acc[q] = make_float4(0.f, 0.f, 0.f, 0.f);

  const float* wr = W + (size_t)n * ldw;
  for (int k0 = 0; k0 < K; k0 += 4) {
    float4 wv = *(const float4*)(wr + k0);
    float wk[4] = {wv.x, wv.y, wv.z, wv.w};
#pragma unroll
    for (int kk = 0; kk < 4; ++kk) {
      const float* a = Ash + (size_t)(k0 + kk) * RP;
      float w = wk[kk];
#pragma unroll
      for (int q = 0; q < ROWS / 4; ++q) {
        float4 av = *(const float4*)(a + 4 * q);
        acc[q].x += w * av.x; acc[q].y += w * av.y;
        acc[q].z += w * av.z; acc[q].w += w * av.w;
      }
    }
  }

  float bv = 0.f;
  if (bias1) bv += bias1[n];
  if (bias2) bv += bias2[n];

#pragma unroll
  for (int q = 0; q < ROWS / 4; ++q) {
    float vs[4] = {acc[q].x, acc[q].y, acc[q].z, acc[q].w};
#pragma unroll
    for (int c = 0; c < 4; ++c) {
      int row = m0 + 4 * q + c;
      if (row < M) {
        float v = vs[c] + bv;
        if (!vmode) {
          if (act == 1) v = fmaxf(v, 0.f);
          else if (act == 2) v = tanhf(v);
          C[(size_t)row * ldc + n] = v;
        } else {
          int bb = row & 63, tt = row >> 6;       // row = t*64 + b
          C[(size_t)bb * 960000 + (size_t)tt * 30000 + n] = v / temp[bb];
        }
      }
    }
  }
}

// ---------------------------------------------------------------------------
// LSTM recurrence: one block per batch item, thread j owns column j.
// gates = gx[t] (x-part + both biases precomputed) + h_{t-1} @ w_hh^T
// ---------------------------------------------------------------------------
__global__ __launch_bounds__(512)
void lstm_kernel(const float* __restrict__ gx, const float* __restrict__ whh,
                 const float* __restrict__ h0, const float* __restrict__ m0,
                 float* __restrict__ h_all)
{
  int b = blockIdx.x, j = threadIdx.x;
  __shared__ __align__(16) float hsh[512];
  hsh[j] = h0[b * 512 + j];
  float mm = m0[b * 512 + j];
  __syncthreads();
  const float4* w0 = (const float4*)(whh + (size_t)j * 512);
  const float4* w1 = (const float4*)(whh + (size_t)(512 + j) * 512);
  const float4* w2 = (const float4*)(whh + (size_t)(1024 + j) * 512);
  const float4* w3 = (const float4*)(whh + (size_t)(1536 + j) * 512);
  for (int t = 0; t < 32; ++t) {
    size_t row = (size_t)t * 64 + b;
    const float* g = gx + row * 2048;
    float a0 = g[j];
    float a1 = g[512 + j];
    float a2 = g[1024 + j];
    float a3 = g[1536 + j];
    for (int k4 = 0; k4 < 128; ++k4) {
      float4 h4 = *(const float4*)(hsh + 4 * k4);
      float4 x0 = w0[k4], x1 = w1[k4], x2 = w2[k4], x3 = w3[k4];
      a0 += x0.x * h4.x + x0.y * h4.y + x0.z * h4.z + x0.w * h4.w;
      a1 += x1.x * h4.x + x1.y * h4.y + x1.z * h4.z + x1.w * h4.w;
      a2 += x2.x * h4.x + x2.y * h4.y + x2.z * h4.z + x2.w * h4.w;
      a3 += x3.x * h4.x + x3.y * h4.y + x3.z * h4.z + x3.w * h4.w;
    }
    float iv = 1.0f / (1.0f + expf(-a0));
    float fv = 1.0f / (1.0f + expf(-a1));
    float gv = tanhf(a2);
    float ov = 1.0f / (1.0f + expf(-a3));
    mm = fv * mm + iv * gv;
    float hn = ov * tanhf(mm);
    __syncthreads();
    hsh[j] = hn;
    h_all[row * 512 + j] = hn;
    __syncthreads();
  }
}

// ---------------------------------------------------------------------------
// attention per (t,b) row: z_p = sum_k tanh(v[b,p,k]+_hh[k])*wz[k] (+zb),
// p=64 uses _s; softmax over 65; c = sum_p a_p feats (raw image rows, raw s);
// ctx = c + hh.
// ---------------------------------------------------------------------------
__global__ __launch_bounds__(256)
void attn_kernel(const float* __restrict__ vbuf, const float* __restrict__ image,
                 const float* __restrict__ hs, const float* __restrict__ hh2,
                 const float* __restrict__ s2, const float* __restrict__ wz,
                 const float* __restrict__ zb, float* __restrict__ attn_out,
                 float* __restrict__ ctx)
{
  int rown = blockIdx.x;            // t*64 + b
  int bb = rown & 63, tt = rown >> 6;
  int tid = threadIdx.x;
  __shared__ float hhsh[512], wzsh[512], ssh[512], zsh[65], ash[65];
  for (int e = tid; e < 512; e += 256) {
    hhsh[e] = hh2[(size_t)rown * 512 + e];
    ssh[e]  = s2[(size_t)rown * 512 + e];
    wzsh[e] = wz[e];
  }
  __syncthreads();
  if (tid < 65) {
    float z = 0.f;
    if (tid < 64) {
      const float* vr = vbuf + (size_t)(bb * 64 + tid) * 512;
      for (int k = 0; k < 512; ++k) z += tanhf(vr[k] + hhsh[k]) * wzsh[k];
    } else {
      for (int k = 0; k < 512; ++k) z += tanhf(ssh[k] + hhsh[k]) * wzsh[k];
    }
    zsh[tid] = z + zb[0];
  }
  __syncthreads();
  if (tid == 0) {
    float m = zsh[0];
    for (int p = 1; p < 65; ++p) m = fmaxf(m, zsh[p]);
    float s = 0.f;
    for (int p = 0; p < 65; ++p) { float e = expf(zsh[p] - m); ash[p] = e; s += e; }
    float inv = 1.0f / s;
    for (int p = 0; p < 65; ++p) ash[p] *= inv;
  }
  __syncthreads();
  size_t aoff = (size_t)bb * 2080 + (size_t)tt * 65;
  if (tid < 65) attn_out[aoff + tid] = ash[tid];
  for (int e = tid; e < 512; e += 256) {
    float c = 0.f;
    for (int p = 0; p < 64; ++p)
      c += ash[p] * image[(size_t)(bb * 64 + p) * 512 + e];
    c += ash[64] * hs[(size_t)rown * 1024 + 512 + e];   // raw s
    c += hs[(size_t)rown * 1024 + e];                   // + hh
    ctx[(size_t)rown * 512 + e] = c;
  }
}

// ---------------------------------------------------------------------------
// per-row (b*32+t) max + logsumexp over 30000 f32 logits in d_out
// ---------------------------------------------------------------------------
__global__ __launch_bounds__(256)
void lse_kernel(const float* __restrict__ out, float* __restrict__ rmax,
                float* __restrict__ lse)
{
  int rflat = blockIdx.x;           // b*32 + t
  const float* row = out + (size_t)rflat * 30000;
  int tid = threadIdx.x;
  __shared__ float red[256];
  float m = -1e30f;
  for (int c = tid; c < 30000; c += 256) m = fmaxf(m, row[c]);
  red[tid] = m; __syncthreads();
  for (int s = 128; s > 0; s >>= 1) {
    if (tid < s) red[tid] = fmaxf(red[tid], red[tid + s]);
    __syncthreads();
  }
  m = red[0]; __syncthreads();
  float sum = 0.f;
  for (int c = tid; c < 30000; c += 256) sum += expf(row[c] - m);
  red[tid] = sum; __syncthreads();
  for (int s = 128; s > 0; s >>= 1) {
    if (tid < s) red[tid] += red[tid + s];
    __syncthreads();
  }
  if (tid == 0) { rmax[rflat] = m; lse[rflat] = m + logf(red[0]); }
}

// ---------------------------------------------------------------------------
// logp = logit - lse (in place)
// ---------------------------------------------------------------------------
__global__ __launch_bounds__(256)
void finalize_kernel(float* __restrict__ out, const float* __restrict__ lse)
{
  size_t idx = (size_t)blockIdx.x * 256 + threadIdx.x;
  if (idx >= 61440000ull) return;
  int rflat = (int)(idx / 30000u);
  out[idx] = out[idx] - lse[rflat];
}

__global__ void slp_kernel(const float* __restrict__ rmax,
                           const float* __restrict__ lse, float* __restrict__ out)
{
  int b = threadIdx.x;              // 64 threads
  float s = 0.f;
  for (int t = 0; t < 32; ++t) s += rmax[b * 32 + t] - lse[b * 32 + t];
  out[61440000 + 133120 + b] = s;
}

// ---------------------------------------------------------------------------
extern "C" void kernel_launch(void* const* d_in, const int* in_sizes, int n_in,
                              void* d_out, int out_size, void* d_ws, size_t ws_size,
                              hipStream_t stream)
{
  const float* image   = (const float*)d_in[0];
  const float* vp      = (const float*)d_in[1];
  const float* lab     = (const float*)d_in[2];
  const float* topic   = (const float*)d_in[3];
  const float* temp    = (const float*)d_in[4];
  const int*   text    = (const int*)d_in[5];
  const float* wemb    = (const float*)d_in[6];
  const float* fc_v_w  = (const float*)d_in[7];
  const float* fc_v_b  = (const float*)d_in[8];
  const float* fc_h_w  = (const float*)d_in[9];
  const float* fc_h_b  = (const float*)d_in[10];
  const float* fc_m_w  = (const float*)d_in[11];
  const float* fc_m_b  = (const float*)d_in[12];
  const float* w_ih    = (const float*)d_in[13];
  const float* w_hh    = (const float*)d_in[14];
  const float* b_ih    = (const float*)d_in[15];
  const float* b_hh    = (const float*)d_in[16];
  const float* fc_w    = (const float*)d_in[17];
  const float* fc_b    = (const float*)d_in[18];
  const float* fc_hh_w = (const float*)d_in[19];
  const float* fc_hh_b = (const float*)d_in[20];
  const float* fc_s_w  = (const float*)d_in[21];
  const float* fc_s_b  = (const float*)d_in[22];
  const float* fc_z_w  = (const float*)d_in[23];
  const float* fc_z_b  = (const float*)d_in[24];
  const float* fc_p_w  = (const float*)d_in[25];
  const float* fc_p_b  = (const float*)d_in[26];
  float* out = (float*)d_out;

  char* base = (char*)d_ws;
  size_t off = 0;
  auto alloc = [&](size_t bytes) -> char* {
    char* p = base + off;
    off += (bytes + 255) & ~(size_t)255;
    return p;
  };
  float* X      = (float*)alloc(2048ull * 1568 * 4);
  float* gxbuf  = (float*)alloc(2048ull * 2048 * 4);
  float* imean  = (float*)alloc(64ull * 512 * 4);
  float* h0b    = (float*)alloc(64ull * 512 * 4);
  float* m0b    = (float*)alloc(64ull * 512 * 4);
  float* vbuf   = (float*)alloc(4096ull * 512 * 4);
  float* h_all  = (float*)alloc(2048ull * 512 * 4);
  float* hsbuf  = (float*)alloc(2048ull * 1024 * 4);
  float* hhbuf  = (float*)alloc(2048ull * 512 * 4);
  float* sbuf   = (float*)alloc(2048ull * 512 * 4);
  float* ctx    = (float*)alloc(2048ull * 512 * 4);
  float* rmaxb  = (float*)alloc(2048ull * 4);
  float* lseb   = (float*)alloc(2048ull * 4);
  (void)in_sizes; (void)n_in; (void)out_size; (void)ws_size;

  mean_kernel<<<64, 256, 0, stream>>>(image, imean);
  prep_kernel<<<64, 256, 0, stream>>>(imean, vp, lab, topic, text, wemb, X);

  // gates_x = X @ w_ih^T + b_ih + b_hh          (M=2048 N=2048 K=1568) ROWS=8
  gemm_tmpl<8><<<dim3(8, 256), 256, 1568 * 12 * 4, stream>>>(
      X, 1568, w_ih, 1568, b_ih, b_hh, gxbuf, 2048, 2048, 2048, 1568, 0, 0, nullptr);
  // v = image @ fc_v_w^T + b                    (M=4096 N=512 K=512) ROWS=32
  gemm_tmpl<32><<<dim3(2, 128), 256, 512 * 36 * 4, stream>>>(
      image, 512, fc_v_w, 512, fc_v_b, nullptr, vbuf, 512, 4096, 512, 512, 0, 0, nullptr);
  // h0 / m0 = tanh(imean @ W^T + b)             (M=64 N=512 K=512)
  gemm_tmpl<32><<<dim3(2, 2), 256, 512 * 36 * 4, stream>>>(
      imean, 512, fc_h_w, 512, fc_h_b, nullptr, h0b, 512, 64, 512, 512, 2, 0, nullptr);
  gemm_tmpl<32><<<dim3(2, 2), 256, 512 * 36 * 4, stream>>>(
      imean, 512, fc_m_w, 512, fc_m_b, nullptr, m0b, 512, 64, 512, 512, 2, 0, nullptr);

  lstm_kernel<<<64, 512, 0, stream>>>(gxbuf, w_hh, h0b, m0b, h_all);

  // hs = relu(h_all @ fc_w^T + b)               (M=2048 N=1024 K=512)
  gemm_tmpl<32><<<dim3(4, 64), 256, 512 * 36 * 4, stream>>>(
      h_all, 512, fc_w, 512, fc_b, nullptr, hsbuf, 1024, 2048, 1024, 512, 1, 0, nullptr);
  // _hh = hh @ fc_hh_w^T + b                    (M=2048 N=512 K=512)
  gemm_tmpl<32><<<dim3(2, 64), 256, 512 * 36 * 4, stream>>>(
      hsbuf, 1024, fc_hh_w, 512, fc_hh_b, nullptr, hhbuf, 512, 2048, 512, 512, 0, 0, nullptr);
  // _s = s @ fc_s_w^T + b
  gemm_tmpl<32><<<dim3(2, 64), 256, 512 * 36 * 4, stream>>>(
      hsbuf + 512, 1024, fc_s_w, 512, fc_s_b, nullptr, sbuf, 512, 2048, 512, 512, 0, 0, nullptr);

  attn_kernel<<<2048, 256, 0, stream>>>(vbuf, image, hsbuf, hhbuf, sbuf,
      fc_z_w, fc_z_b, out + 61440000, ctx);

  // logits = (ctx @ fc_p_w^T + b) / temp  -> out[b][t][v]   (M=2048 N=30000 K=512)
  gemm_tmpl<32><<<dim3(118, 64), 256, 512 * 36 * 4, stream>>>(
      ctx, 512, fc_p_w, 512, fc_p_b, nullptr, out, 0, 2048, 30000, 512, 0, 1, temp);

  lse_kernel<<<2048, 256, 0, stream>>>(out, rmaxb, lseb);
  finalize_kernel<<<240000, 256, 0, stream>>>(out, lseb);
  slp_kernel<<<1, 64, 0, stream>>>(rmaxb, lseb, out);
}

// Round 4
// 1724.473 us; speedup vs baseline: 4.2937x; 4.2937x over previous
//
#include <hip/hip_runtime.h>

// ---------------------------------------------------------------------------
// SentenceDecoder on MI355X — f32 I/O, bf16 MFMA internals.
// Dims: B=64, T=32, P=64, E=H=512, V=30000, IN=1568, rows = T*B = 2048.
// Output (flat f32): logp [64][32][30000] | attn [64][32][65] | slp [64]
// ---------------------------------------------------------------------------

typedef unsigned short bf16u;
typedef __attribute__((ext_vector_type(8))) short short8;   // MFMA A/B frag
typedef __attribute__((ext_vector_type(4))) float floatx4;  // MFMA C/D frag

#define DEV __device__ __forceinline__

DEV float b2f(bf16u u) { return __uint_as_float(((unsigned)u) << 16); }
DEV bf16u f2b(float f) {
  unsigned u = __float_as_uint(f);
  u = (u + 0x7fffu + ((u >> 16) & 1u)) >> 16;   // RNE
  return (bf16u)u;
}

// ---------------------------------------------------------------------------
// f32 -> bf16 conversion
// ---------------------------------------------------------------------------
__global__ __launch_bounds__(256)
void cvt_kernel(const float* __restrict__ src, bf16u* __restrict__ dst, int n)
{
  int i = blockIdx.x * 256 + threadIdx.x;
  if (i < n) dst[i] = f2b(src[i]);
}

// ---------------------------------------------------------------------------
// image mean over P=64 (f32)
// ---------------------------------------------------------------------------
__global__ __launch_bounds__(256)
void mean_kernel(const float* __restrict__ image, float* __restrict__ imean)
{
  int b = blockIdx.x;
  for (int e = threadIdx.x; e < 512; e += 256) {
    float s = 0.f;
    for (int p = 0; p < 64; ++p) s += image[(size_t)(b * 64 + p) * 512 + e];
    imean[b * 512 + e] = s * (1.0f / 64.0f);
  }
}

// ---------------------------------------------------------------------------
// X[t*64+b] (bf16) = [imean | vp | label | topic | emb[tok]]  width 1568
// ---------------------------------------------------------------------------
__global__ __launch_bounds__(256)
void prep_kernel(const float* __restrict__ imean, const float* __restrict__ vp,
                 const float* __restrict__ lab, const float* __restrict__ topic,
                 const int* __restrict__ text, const float* __restrict__ wemb,
                 bf16u* __restrict__ X)
{
  int b = blockIdx.x;
  for (int t = 0; t < 32; ++t) {
    bf16u* xr = X + ((size_t)t * 64 + b) * 1568;
    int tok = (t == 0) ? 0 : text[b * 32 + t - 1];
    for (int e = threadIdx.x; e < 512; e += 256) {
      xr[e] = f2b(imean[b * 512 + e]);
      xr[544 + e] = f2b(topic[b * 512 + e]);
      xr[1056 + e] = f2b(wemb[(size_t)tok * 512 + e]);
    }
    if (threadIdx.x < 16) {
      xr[512 + threadIdx.x] = f2b(vp[b * 16 + threadIdx.x]);
      xr[528 + threadIdx.x] = f2b(lab[b * 16 + threadIdx.x]);
    }
  }
}

// ---------------------------------------------------------------------------
// pack w_hh [2048][512] f32 -> bf16 wpack[blk][kg][rr][8]
// blk = (row&511)>>4, lc = row&15, gate = row>>9, rr = gate*16+lc, kg = k>>3
// ---------------------------------------------------------------------------
__global__ __launch_bounds__(256)
void pack_whh(const float* __restrict__ whh, bf16u* __restrict__ wpack)
{
  int idx = blockIdx.x * 256 + threadIdx.x;   // 2048*512
  int gr = idx >> 9, k = idx & 511;
  int gate = gr >> 9, win = gr & 511;
  int blk = win >> 4, lc = win & 15;
  int rr = gate * 16 + lc;
  wpack[(size_t)blk * 32768 + (((k >> 3) * 64 + rr) << 3) + (k & 7)] =
      f2b(whh[(size_t)gr * 512 + k]);
}

// ---------------------------------------------------------------------------
// MFMA GEMM (m97 pattern): C[m,n] = act( A[m,:].W[n,:] + bias1 (+bias2) )
// A: M x K bf16 (lda), W: N x K bf16 (ldw).  128x128 tile, BK=32, 2x2 waves.
// MODE 1: vocab epilogue (f32 logits/temp to out[b][t][v] + per-64col stats)
// MODE 2: bf16 store to C.
// ---------------------------------------------------------------------------
#define BK 32
#define LDT 40

template<int MODE>
__global__ __launch_bounds__(256)
void gemm_bt(const bf16u* __restrict__ A, int lda,
             const bf16u* __restrict__ W, int ldw,
             const float* __restrict__ bias1, const float* __restrict__ bias2,
             bf16u* __restrict__ C, int ldc,
             int M, int N, int K, int act,
             const float* __restrict__ temp,
             float* __restrict__ outbase,
             float* __restrict__ pmax, float* __restrict__ psum)
{
  __shared__ __align__(16) bf16u As[128 * LDT];
  __shared__ __align__(16) bf16u Ws[128 * LDT];
  const int tid = threadIdx.x;
  const int n0 = blockIdx.x * 128;
  const int m0 = blockIdx.y * 128;
  const int wave = tid >> 6, lane = tid & 63;
  const int wm = wave >> 1, wn = wave & 1;
  const int q = lane >> 4, l16 = lane & 15;
  const int r0 = tid >> 2, s0 = tid & 3;

  const floatx4 zero = {0.f, 0.f, 0.f, 0.f};
  floatx4 acc[4][4];
#pragma unroll
  for (int i = 0; i < 4; ++i)
#pragma unroll
    for (int j = 0; j < 4; ++j) acc[i][j] = zero;

  int ar0 = m0 + r0;      if (ar0 >= M) ar0 = M - 1;
  int ar1 = m0 + r0 + 64; if (ar1 >= M) ar1 = M - 1;
  int wr0 = n0 + r0;      if (wr0 >= N) wr0 = N - 1;
  int wr1 = n0 + r0 + 64; if (wr1 >= N) wr1 = N - 1;
  const bf16u* Ap0 = A + (size_t)ar0 * lda + s0 * 8;
  const bf16u* Ap1 = A + (size_t)ar1 * lda + s0 * 8;
  const bf16u* Wp0 = W + (size_t)wr0 * ldw + s0 * 8;
  const bf16u* Wp1 = W + (size_t)wr1 * ldw + s0 * 8;

  for (int k0 = 0; k0 < K; k0 += BK) {
    const int4 a0 = *(const int4*)(Ap0 + k0);
    const int4 a1 = *(const int4*)(Ap1 + k0);
    const int4 w0 = *(const int4*)(Wp0 + k0);
    const int4 w1 = *(const int4*)(Wp1 + k0);
    __syncthreads();
    *(int4*)(As + r0 * LDT + s0 * 8) = a0;
    *(int4*)(As + (r0 + 64) * LDT + s0 * 8) = a1;
    *(int4*)(Ws + r0 * LDT + s0 * 8) = w0;
    *(int4*)(Ws + (r0 + 64) * LDT + s0 * 8) = w1;
    __syncthreads();
    short8 af[4], wf[4];
#pragma unroll
    for (int i = 0; i < 4; ++i) {
      af[i] = *(const short8*)(As + (wm * 64 + i * 16 + l16) * LDT + q * 8);
      wf[i] = *(const short8*)(Ws + (wn * 64 + i * 16 + l16) * LDT + q * 8);
    }
#pragma unroll
    for (int i = 0; i < 4; ++i)
#pragma unroll
      for (int j = 0; j < 4; ++j)
        acc[i][j] = __builtin_amdgcn_mfma_f32_16x16x32_bf16(af[i], wf[j], acc[i][j], 0, 0, 0);
  }

  // C/D layout: col = lane&15, row = (lane>>4)*4 + reg
  int colb[4]; float bias[4];
#pragma unroll
  for (int j = 0; j < 4; ++j) {
    int col = n0 + wn * 64 + j * 16 + l16;
    colb[j] = col;
    int cc = col < N ? col : N - 1;
    float bv = 0.f;
    if (bias1) bv += bias1[cc];
    if (bias2) bv += bias2[cc];
    bias[j] = bv;
  }

  if (MODE == 2) {
#pragma unroll
    for (int i = 0; i < 4; ++i) {
#pragma unroll
      for (int r = 0; r < 4; ++r) {
        int row = m0 + wm * 64 + i * 16 + q * 4 + r;
        if (row < M) {
#pragma unroll
          for (int j = 0; j < 4; ++j) {
            int col = colb[j];
            if (col < N) {
              float v = acc[i][j][r] + bias[j];
              if (act == 1) v = fmaxf(v, 0.f);
              C[(size_t)row * ldc + col] = f2b(v);
            }
          }
        }
      }
    }
  } else {   // MODE 1: vocab
    int pc = blockIdx.x * 2 + wn;   // 64-col slice (< 470)
#pragma unroll
    for (int i = 0; i < 4; ++i) {
#pragma unroll
      for (int r = 0; r < 4; ++r) {
        int row = m0 + wm * 64 + i * 16 + q * 4 + r;   // t*64 + b
        int bb = row & 63, tt = row >> 6;
        float rt = 1.0f / temp[bb];
        float vals[4];
#pragma unroll
        for (int j = 0; j < 4; ++j) {
          int col = colb[j];
          float v = (acc[i][j][r] + bias[j]) * rt;
          if (col < N) {
            outbase[(size_t)bb * 960000 + (size_t)tt * 30000 + col] = v;
            vals[j] = v;
          } else vals[j] = -1e30f;
        }
        float mx = fmaxf(fmaxf(vals[0], vals[1]), fmaxf(vals[2], vals[3]));
#pragma unroll
        for (int off = 1; off < 16; off <<= 1) mx = fmaxf(mx, __shfl_xor(mx, off));
        float s = 0.f;
#pragma unroll
        for (int j = 0; j < 4; ++j)
          s += (vals[j] > -1e29f) ? __expf(vals[j] - mx) : 0.f;
#pragma unroll
        for (int off = 1; off < 16; off <<= 1) s += __shfl_xor(s, off);
        if (l16 == 0) {
          pmax[(size_t)row * 470 + pc] = mx;
          psum[(size_t)row * 470 + pc] = s;
        }
      }
    }
  }
}

// ---------------------------------------------------------------------------
// scalar f32 GEMM for tiny h0/m0 (M=64)
// ---------------------------------------------------------------------------
template<int ROWS>
__global__ void gemm_tmpl(const float* __restrict__ A, int lda,
                          const float* __restrict__ W, int ldw,
                          const float* __restrict__ bias1,
                          float* __restrict__ C, int ldc,
                          int M, int N, int K, int act)
{
  constexpr int RP = ROWS + 4;
  extern __shared__ __align__(16) float Ash[];
  const int tid = threadIdx.x;
  const int m0 = blockIdx.y * ROWS;
  const int n0 = blockIdx.x * 256;
  for (int idx = tid; idx < ROWS * K; idx += 256) {
    int r = idx / K, k = idx - r * K;
    int rr = m0 + r; if (rr >= M) rr = M - 1;
    Ash[k * RP + r] = A[(size_t)rr * lda + k];
  }
  __syncthreads();
  int n = n0 + tid;
  if (n >= N) return;
  float acc[ROWS];
#pragma unroll
  for (int r = 0; r < ROWS; ++r) acc[r] = 0.f;
  const float* wr = W + (size_t)n * ldw;
  for (int k = 0; k < K; ++k) {
    float w = wr[k];
    const float* a = Ash + (size_t)k * RP;
#pragma unroll
    for (int r = 0; r < ROWS; ++r) acc[r] += w * a[r];
  }
  float bv = bias1 ? bias1[n] : 0.f;
#pragma unroll
  for (int r = 0; r < ROWS; ++r) {
    int row = m0 + r;
    if (row < M) {
      float v = acc[r] + bv;
      if (act == 1) v = fmaxf(v, 0.f);
      else if (act == 2) v = tanhf(v);
      C[(size_t)row * ldc + n] = v;
    }
  }
}

// ---------------------------------------------------------------------------
// init LSTM state: pack h0 (f32) into packed bf16 layout, copy m0 f32
// packed pos for h[b][jj]: ((jj>>3)*64 + b)*8 + (jj&7)
// ---------------------------------------------------------------------------
__global__ __launch_bounds__(256)
void init_state(const float* __restrict__ h0b, const float* __restrict__ m0b,
                bf16u* __restrict__ hOut, float* __restrict__ mbuf)
{
  int i = blockIdx.x * 256 + threadIdx.x;   // 32768
  int b = i >> 9, jj = i & 511;
  hOut[(((jj >> 3) * 64 + b) << 3) + (jj & 7)] = f2b(h0b[i]);
  mbuf[i] = m0b[i];
}

// ---------------------------------------------------------------------------
// LSTM timestep (launched 32x): 32 blocks, block owns 16 h-cols (64 gate rows).
// LDS: h packed (64KB) + weight slice packed (64KB) + gates f32 (16.6KB).
// gates[b][rr] = h@wslice^T via MFMA; pointwise -> hOut (packed), h_all, mbuf.
// ---------------------------------------------------------------------------
__global__ __launch_bounds__(256)
void lstm_step(const bf16u* __restrict__ wpack, const bf16u* __restrict__ gx,
               const bf16u* __restrict__ hIn, bf16u* __restrict__ hOut,
               float* __restrict__ mbuf, bf16u* __restrict__ h_all, int t)
{
  extern __shared__ __align__(16) char smem[];
  bf16u* hsh = (bf16u*)smem;                 // 32768 bf16, [kg][b][8]
  bf16u* wsh = (bf16u*)(smem + 65536);       // 32768 bf16, [kg][rr][8]
  float* gsh = (float*)(smem + 131072);      // [64][65]
  const int blk = blockIdx.x, tid = threadIdx.x;

  const int4* hsrc = (const int4*)hIn;
  const int4* wsrc = (const int4*)(wpack + (size_t)blk * 32768);
  int4* hdst = (int4*)hsh; int4* wdst = (int4*)wsh;
#pragma unroll
  for (int u = 0; u < 16; ++u) {             // 4096 int4 each
    hdst[tid + 256 * u] = hsrc[tid + 256 * u];
    wdst[tid + 256 * u] = wsrc[tid + 256 * u];
  }
  __syncthreads();

  const int wave = tid >> 6, lane = tid & 63;
  const int wm = wave >> 1, wn = wave & 1, q = lane >> 4, l16 = lane & 15;
  const floatx4 zero = {0.f, 0.f, 0.f, 0.f};
  floatx4 acc[2][2];
#pragma unroll
  for (int i = 0; i < 2; ++i)
#pragma unroll
    for (int j = 0; j < 2; ++j) acc[i][j] = zero;

  for (int s = 0; s < 16; ++s) {
    short8 af[2], wf[2];
#pragma unroll
    for (int i = 0; i < 2; ++i)
      af[i] = *(const short8*)(hsh + ((((s * 4 + q) * 64) + wm * 32 + i * 16 + l16) << 3));
#pragma unroll
    for (int j = 0; j < 2; ++j)
      wf[j] = *(const short8*)(wsh + ((((s * 4 + q) * 64) + wn * 32 + j * 16 + l16) << 3));
#pragma unroll
    for (int i = 0; i < 2; ++i)
#pragma unroll
      for (int j = 0; j < 2; ++j)
        acc[i][j] = __builtin_amdgcn_mfma_f32_16x16x32_bf16(af[i], wf[j], acc[i][j], 0, 0, 0);
  }
  // D: col(rr) = lane&15 (+tile), row(b) = q*4+reg (+tile)
#pragma unroll
  for (int i = 0; i < 2; ++i)
#pragma unroll
    for (int j = 0; j < 2; ++j)
#pragma unroll
      for (int r = 0; r < 4; ++r)
        gsh[(wn * 32 + j * 16 + l16) * 65 + (wm * 32 + i * 16 + q * 4 + r)] = acc[i][j][r];
  __syncthreads();

#pragma unroll
  for (int u = 0; u < 4; ++u) {
    int p = tid + 256 * u;            // 1024 pairs
    int b = p >> 4, lc = p & 15;
    int jj = blk * 16 + lc;
    const bf16u* gxr = gx + ((size_t)t * 64 + b) * 2048;
    float ai = gsh[(lc) * 65 + b]        + b2f(gxr[jj]);
    float af = gsh[(16 + lc) * 65 + b]   + b2f(gxr[512 + jj]);
    float ag = gsh[(32 + lc) * 65 + b]   + b2f(gxr[1024 + jj]);
    float ao = gsh[(48 + lc) * 65 + b]   + b2f(gxr[1536 + jj]);
    float iv = 1.f / (1.f + __expf(-ai));
    float fv = 1.f / (1.f + __expf(-af));
    float gv = tanhf(ag);
    float ov = 1.f / (1.f + __expf(-ao));
    float mm = fv * mbuf[b * 512 + jj] + iv * gv;
    float hn = ov * tanhf(mm);
    mbuf[b * 512 + jj] = mm;
    bf16u hb = f2b(hn);
    hOut[(((jj >> 3) * 64 + b) << 3) + (jj & 7)] = hb;
    h_all[((size_t)t * 64 + b) * 512 + jj] = hb;
  }
}

// ---------------------------------------------------------------------------
// attention per (t,b) row
// ---------------------------------------------------------------------------
__global__ __launch_bounds__(256)
void attn_kernel(const bf16u* __restrict__ vbuf, const float* __restrict__ image,
                 const bf16u* __restrict__ hs_bf, const bf16u* __restrict__ hh2,
                 const bf16u* __restrict__ s2, const float* __restrict__ wz,
                 const float* __restrict__ zb, float* __restrict__ attn_out,
                 bf16u* __restrict__ ctx)
{
  int rown = blockIdx.x;            // t*64 + b
  int bb = rown & 63, tt = rown >> 6;
  int tid = threadIdx.x;
  __shared__ float hhsh[512], wzsh[512], ssh[512];
  __shared__ float zpart[65][4];
  __shared__ float zsh[65], ash[65];
  for (int e = tid; e < 512; e += 256) {
    hhsh[e] = b2f(hh2[(size_t)rown * 512 + e]);
    ssh[e]  = b2f(s2[(size_t)rown * 512 + e]);
    wzsh[e] = wz[e];
  }
  __syncthreads();
  {
    int p = tid >> 2, qq = tid & 3;
    const bf16u* vr = vbuf + (size_t)(bb * 64 + p) * 512;
    float s = 0.f;
    for (int k = qq * 128; k < qq * 128 + 128; ++k)
      s += tanhf(b2f(vr[k]) + hhsh[k]) * wzsh[k];
    zpart[p][qq] = s;
    if (tid < 4) {
      float s2p = 0.f;
      for (int k = tid * 128; k < tid * 128 + 128; ++k)
        s2p += tanhf(ssh[k] + hhsh[k]) * wzsh[k];
      zpart[64][tid] = s2p;
    }
  }
  __syncthreads();
  if (tid < 65)
    zsh[tid] = zpart[tid][0] + zpart[tid][1] + zpart[tid][2] + zpart[tid][3] + zb[0];
  __syncthreads();
  if (tid == 0) {
    float m = zsh[0];
    for (int p = 1; p < 65; ++p) m = fmaxf(m, zsh[p]);
    float s = 0.f;
    for (int p = 0; p < 65; ++p) { float e = __expf(zsh[p] - m); ash[p] = e; s += e; }
    float inv = 1.0f / s;
    for (int p = 0; p < 65; ++p) ash[p] *= inv;
  }
  __syncthreads();
  size_t aoff = (size_t)bb * 2080 + (size_t)tt * 65;
  if (tid < 65) attn_out[aoff + tid] = ash[tid];
  for (int e = tid; e < 512; e += 256) {
    float c = 0.f;
    for (int p = 0; p < 64; ++p)
      c += ash[p] * image[(size_t)(bb * 64 + p) * 512 + e];
    c += ash[64] * b2f(hs_bf[(size_t)rown * 1024 + 512 + e]);   // raw s
    c += b2f(hs_bf[(size_t)rown * 1024 + e]);                   // + hh
    ctx[(size_t)rown * 512 + e] = f2b(c);
  }
}

// ---------------------------------------------------------------------------
// combine per-64col partials -> lse & rowmax (rows indexed t*64+b)
// ---------------------------------------------------------------------------
__global__ __launch_bounds__(256)
void reduce_lse(const float* __restrict__ pmax, const float* __restrict__ psum,
                float* __restrict__ lse, float* __restrict__ rmax)
{
  int row = blockIdx.x * 256 + threadIdx.x;
  if (row >= 2048) return;
  float m = -1e30f, s = 0.f;
  for (int c = 0; c < 470; ++c) {
    float mi = pmax[(size_t)row * 470 + c];
    float si = psum[(size_t)row * 470 + c];
    if (mi > m) { s = s * __expf(m - mi) + si; m = mi; }
    else        { s += si * __expf(mi - m); }
  }
  rmax[row] = m;
  lse[row] = m + logf(s);
}

// ---------------------------------------------------------------------------
// logp = logit - lse (in place, float4).  out row rflat = b*32+t.
// ---------------------------------------------------------------------------
__global__ __launch_bounds__(256)
void finalize_kernel(float* __restrict__ out, const float* __restrict__ lse)
{
  int idx = blockIdx.x * 256 + threadIdx.x;   // 15,360,000 float4s
  if (idx >= 15360000) return;
  int rflat = idx / 7500;
  int c4 = idx - rflat * 7500;
  float L = lse[(rflat & 31) * 64 + (rflat >> 5)];
  float4* p = (float4*)(out + (size_t)rflat * 30000 + (size_t)c4 * 4);
  float4 v = *p;
  v.x -= L; v.y -= L; v.z -= L; v.w -= L;
  *p = v;
}

__global__ void slp_kernel(const float* __restrict__ rmax,
                           const float* __restrict__ lse, float* __restrict__ out)
{
  int b = threadIdx.x;              // 64 threads
  float s = 0.f;
  for (int t = 0; t < 32; ++t) { int r = t * 64 + b; s += rmax[r] - lse[r]; }
  out[61440000 + 133120 + b] = s;
}

// ---------------------------------------------------------------------------
extern "C" void kernel_launch(void* const* d_in, const int* in_sizes, int n_in,
                              void* d_out, int out_size, void* d_ws, size_t ws_size,
                              hipStream_t stream)
{
  const float* image   = (const float*)d_in[0];
  const float* vp      = (const float*)d_in[1];
  const float* lab     = (const float*)d_in[2];
  const float* topic   = (const float*)d_in[3];
  const float* temp    = (const float*)d_in[4];
  const int*   text    = (const int*)d_in[5];
  const float* wemb    = (const float*)d_in[6];
  const float* fc_v_w  = (const float*)d_in[7];
  const float* fc_v_b  = (const float*)d_in[8];
  const float* fc_h_w  = (const float*)d_in[9];
  const float* fc_h_b  = (const float*)d_in[10];
  const float* fc_m_w  = (const float*)d_in[11];
  const float* fc_m_b  = (const float*)d_in[12];
  const float* w_ih    = (const float*)d_in[13];
  const float* w_hh    = (const float*)d_in[14];
  const float* b_ih    = (const float*)d_in[15];
  const float* b_hh    = (const float*)d_in[16];
  const float* fc_w    = (const float*)d_in[17];
  const float* fc_b    = (const float*)d_in[18];
  const float* fc_hh_w = (const float*)d_in[19];
  const float* fc_hh_b = (const float*)d_in[20];
  const float* fc_s_w  = (const float*)d_in[21];
  const float* fc_s_b  = (const float*)d_in[22];
  const float* fc_z_w  = (const float*)d_in[23];
  const float* fc_z_b  = (const float*)d_in[24];
  const float* fc_p_w  = (const float*)d_in[25];
  const float* fc_p_b  = (const float*)d_in[26];
  float* out = (float*)d_out;

  char* base = (char*)d_ws;
  size_t off = 0;
  auto alloc = [&](size_t bytes) -> char* {
    char* p = base + off;
    off += (bytes + 255) & ~(size_t)255;
    return p;
  };
  bf16u* X       = (bf16u*)alloc(2048ull * 1568 * 2);   // dead after gates gemm
  bf16u* w_ih_bf = (bf16u*)alloc(2048ull * 1568 * 2);   // dead after gates gemm
  bf16u* gx_bf   = (bf16u*)alloc(2048ull * 2048 * 2);   // dead after lstm
  bf16u* image_bf= (bf16u*)alloc(4096ull * 512 * 2);    // dead after v gemm
  bf16u* wpackb  = (bf16u*)alloc(2048ull * 512 * 2);
  bf16u* fcv_bf  = (bf16u*)alloc(512ull * 512 * 2);
  bf16u* fcw_bf  = (bf16u*)alloc(1024ull * 512 * 2);
  bf16u* fchh_bf = (bf16u*)alloc(512ull * 512 * 2);
  bf16u* fcs_bf  = (bf16u*)alloc(512ull * 512 * 2);
  bf16u* fcp_bf  = (bf16u*)alloc(30000ull * 512 * 2);
  float* imean   = (float*)alloc(64ull * 512 * 4);
  float* h0b     = (float*)alloc(64ull * 512 * 4);
  float* m0b     = (float*)alloc(64ull * 512 * 4);
  bf16u* vbuf    = (bf16u*)alloc(4096ull * 512 * 2);
  bf16u* hA      = (bf16u*)alloc(64ull * 512 * 2);
  bf16u* hB      = (bf16u*)alloc(64ull * 512 * 2);
  float* mbuf    = (float*)alloc(64ull * 512 * 4);
  bf16u* h_all   = (bf16u*)alloc(2048ull * 512 * 2);
  float* rmaxb   = (float*)alloc(2048ull * 4);
  float* lseb    = (float*)alloc(2048ull * 4);
  // overlays (regions dead by the time these are written):
  bf16u* hs_bf   = (bf16u*)w_ih_bf;                     // 2048x1024 bf16 (4.2MB <= 6.4MB)
  bf16u* ctx     = (bf16u*)(w_ih_bf + 2048ull * 1024);  // 2048x512 bf16 (fits)
  bf16u* hhbuf   = (bf16u*)X;                           // 2048x512 bf16
  bf16u* sbuf    = (bf16u*)(X + 2048ull * 512);         // 2048x512 bf16 (fits in X)
  float* pmaxb   = (float*)gx_bf;                       // 2048x470 f32
  float* psumb   = (float*)(gx_bf + 2048ull * 2048);    // second half of gx region
  (void)in_sizes; (void)n_in; (void)out_size; (void)ws_size;

  // --- prep & conversions ---
  mean_kernel<<<64, 256, 0, stream>>>(image, imean);
  prep_kernel<<<64, 256, 0, stream>>>(imean, vp, lab, topic, text, wemb, X);
  cvt_kernel<<<12544, 256, 0, stream>>>(w_ih, w_ih_bf, 2048 * 1568);
  cvt_kernel<<<8192, 256, 0, stream>>>(image, image_bf, 4096 * 512);
  cvt_kernel<<<1024, 256, 0, stream>>>(fc_v_w, fcv_bf, 512 * 512);
  cvt_kernel<<<2048, 256, 0, stream>>>(fc_w, fcw_bf, 1024 * 512);
  cvt_kernel<<<1024, 256, 0, stream>>>(fc_hh_w, fchh_bf, 512 * 512);
  cvt_kernel<<<1024, 256, 0, stream>>>(fc_s_w, fcs_bf, 512 * 512);
  cvt_kernel<<<60000, 256, 0, stream>>>(fc_p_w, fcp_bf, 30000 * 512);
  pack_whh<<<4096, 256, 0, stream>>>(w_hh, wpackb);

  // gates_x = X @ w_ih^T + b_ih + b_hh  (2048x2048x1568) -> bf16
  gemm_bt<2><<<dim3(16, 16), 256, 0, stream>>>(X, 1568, w_ih_bf, 1568, b_ih, b_hh,
      gx_bf, 2048, 2048, 2048, 1568, 0, nullptr, nullptr, nullptr, nullptr);
  // v = image @ fc_v_w^T + b  (4096x512x512) -> bf16
  gemm_bt<2><<<dim3(4, 32), 256, 0, stream>>>(image_bf, 512, fcv_bf, 512, fc_v_b, nullptr,
      vbuf, 512, 4096, 512, 512, 0, nullptr, nullptr, nullptr, nullptr);
  // h0 / m0 scalar f32 (tiny)
  gemm_tmpl<32><<<dim3(2, 2), 256, 512 * 36 * 4, stream>>>(
      imean, 512, fc_h_w, 512, fc_h_b, h0b, 512, 64, 512, 512, 2);
  gemm_tmpl<32><<<dim3(2, 2), 256, 512 * 36 * 4, stream>>>(
      imean, 512, fc_m_w, 512, fc_m_b, m0b, 512, 64, 512, 512, 2);

  // --- LSTM: 32 per-timestep MFMA launches ---
  init_state<<<128, 256, 0, stream>>>(h0b, m0b, hA, mbuf);
  const int lstm_lds = 65536 + 65536 + 64 * 65 * 4;   // 147,712 B
  for (int t = 0; t < 32; ++t) {
    const bf16u* hi = (t & 1) ? hB : hA;
    bf16u* ho = (t & 1) ? hA : hB;
    lstm_step<<<32, 256, lstm_lds, stream>>>(wpackb, gx_bf, hi, ho, mbuf, h_all, t);
  }

  // hs = relu(h_all @ fc_w^T + b)  (2048x1024x512) -> bf16
  gemm_bt<2><<<dim3(8, 16), 256, 0, stream>>>(h_all, 512, fcw_bf, 512, fc_b, nullptr,
      hs_bf, 1024, 2048, 1024, 512, 1, nullptr, nullptr, nullptr, nullptr);
  // _hh / _s  (2048x512x512) -> bf16
  gemm_bt<2><<<dim3(4, 16), 256, 0, stream>>>(hs_bf, 1024, fchh_bf, 512, fc_hh_b, nullptr,
      hhbuf, 512, 2048, 512, 512, 0, nullptr, nullptr, nullptr, nullptr);
  gemm_bt<2><<<dim3(4, 16), 256, 0, stream>>>(hs_bf + 512, 1024, fcs_bf, 512, fc_s_b, nullptr,
      sbuf, 512, 2048, 512, 512, 0, nullptr, nullptr, nullptr, nullptr);

  attn_kernel<<<2048, 256, 0, stream>>>(vbuf, image, hs_bf, hhbuf, sbuf,
      fc_z_w, fc_z_b, out + 61440000, ctx);

  // vocab projection + fused softmax stats (2048x30000x512)
  gemm_bt<1><<<dim3(235, 16), 256, 0, stream>>>(ctx, 512, fcp_bf, 512, fc_p_b, nullptr,
      nullptr, 0, 2048, 30000, 512, 0, temp, out, pmaxb, psumb);

  reduce_lse<<<8, 256, 0, stream>>>(pmaxb, psumb, lseb, rmaxb);
  finalize_kernel<<<60000, 256, 0, stream>>>(out, lseb);
  slp_kernel<<<1, 64, 0, stream>>>(rmaxb, lseb, out);
}